// Round 2
// baseline (7899.703 us; speedup 1.0000x reference)
//
#include <hip/hip_runtime.h>

#define NB 2
#define TSTEPS 512
#define INPUT_D 6

__device__ __forceinline__ float sigf(float x) {
    return 1.0f / (1.0f + __expf(-x));
}
__device__ __forceinline__ float tanh_fast(float x) {
    // 1 - 2/(exp(2x)+1); saturates correctly at +/-inf
    return 1.0f - 2.0f / (__expf(2.0f * x) + 1.0f);
}

__global__ __launch_bounds__(256, 2)
void lstm_fused_kernel(const float* __restrict__ x,
                       const float* __restrict__ W_ih0, const float* __restrict__ W_hh0,
                       const float* __restrict__ b_ih0, const float* __restrict__ b_hh0,
                       const float* __restrict__ W_ih1, const float* __restrict__ W_hh1,
                       const float* __restrict__ b_ih1, const float* __restrict__ b_hh1,
                       const float* __restrict__ W_fc1, const float* __restrict__ b_fc1,
                       const float* __restrict__ W_fc2, const float* __restrict__ b_fc2,
                       float* __restrict__ out)
{
    const int g  = threadIdx.x;          // gate row 0..255
    const int b0 = blockIdx.x * NB;      // first batch element of this WG

    // ---------------- per-thread weights in registers ----------------
    float wih0[INPUT_D];
#pragma unroll
    for (int d = 0; d < INPUT_D; ++d) wih0[d] = W_ih0[g * INPUT_D + d];

    float whh0[64], wih1[64], whh1[64];
    {
        const float4* p0 = (const float4*)(W_hh0 + g * 64);
        const float4* p1 = (const float4*)(W_ih1 + g * 64);
        const float4* p2 = (const float4*)(W_hh1 + g * 64);
#pragma unroll
        for (int k4 = 0; k4 < 16; ++k4) {
            float4 a = p0[k4];
            whh0[4*k4+0] = a.x; whh0[4*k4+1] = a.y; whh0[4*k4+2] = a.z; whh0[4*k4+3] = a.w;
            float4 b = p1[k4];
            wih1[4*k4+0] = b.x; wih1[4*k4+1] = b.y; wih1[4*k4+2] = b.z; wih1[4*k4+3] = b.w;
            float4 c = p2[k4];
            whh1[4*k4+0] = c.x; whh1[4*k4+1] = c.y; whh1[4*k4+2] = c.z; whh1[4*k4+3] = c.w;
        }
    }
    const float bias0 = b_ih0[g] + b_hh0[g];
    const float bias1 = b_ih1[g] + b_hh1[g];
    const int typ = g >> 6;   // 0=i 1=f 2=g 3=o  (wave-uniform)

    // ---------------- LDS ----------------
    __shared__ __align__(16) float h1buf[NB][64];
    __shared__ __align__(16) float h2buf[NB][64];
    __shared__ __align__(16) float gbuf[NB][256];
    __shared__ float fcbuf[NB][32];

    if (g < NB * 64) {
        const int bb = g >> 6, j = g & 63;
        h1buf[bb][j] = 0.0f;
        h2buf[bb][j] = 0.0f;
    }
    float c1 = 0.0f, c2 = 0.0f;            // cell state, owned by threads < NB*64
    const int ubb = g >> 6, uj = g & 63;   // update-phase mapping

    // x prefetch double-buffer (uniform-address loads)
    float xcur[NB][INPUT_D];
#pragma unroll
    for (int b = 0; b < NB; ++b)
#pragma unroll
        for (int d = 0; d < INPUT_D; ++d)
            xcur[b][d] = x[((b0 + b) * TSTEPS + 0) * INPUT_D + d];

    __syncthreads();

    for (int t = 0; t < TSTEPS; ++t) {
        // issue next step's x loads early (hidden under compute)
        const int tn = (t + 1 < TSTEPS) ? (t + 1) : (TSTEPS - 1);
        float xnxt[NB][INPUT_D];
#pragma unroll
        for (int b = 0; b < NB; ++b)
#pragma unroll
            for (int d = 0; d < INPUT_D; ++d)
                xnxt[b][d] = x[((b0 + b) * TSTEPS + tn) * INPUT_D + d];

        // ---------------- layer 1 gates ----------------
        float acc[NB];
#pragma unroll
        for (int b = 0; b < NB; ++b) {
            float a = bias0;
#pragma unroll
            for (int d = 0; d < INPUT_D; ++d) a = fmaf(wih0[d], xcur[b][d], a);
            acc[b] = a;
        }
#pragma unroll
        for (int b = 0; b < NB; ++b) {
            const float4* hv = (const float4*)h1buf[b];
            float a = acc[b];
#pragma unroll
            for (int k4 = 0; k4 < 16; ++k4) {
                float4 h = hv[k4];
                a = fmaf(whh0[4*k4+0], h.x, a);
                a = fmaf(whh0[4*k4+1], h.y, a);
                a = fmaf(whh0[4*k4+2], h.z, a);
                a = fmaf(whh0[4*k4+3], h.w, a);
            }
            acc[b] = a;
        }
#pragma unroll
        for (int b = 0; b < NB; ++b)
            gbuf[b][g] = (typ == 2) ? tanh_fast(acc[b]) : sigf(acc[b]);
        __syncthreads();

        // ---------------- layer 1 cell/hidden update ----------------
        if (g < NB * 64) {
            const float iv = gbuf[ubb][uj];
            const float fv = gbuf[ubb][64 + uj];
            const float gv = gbuf[ubb][128 + uj];
            const float ov = gbuf[ubb][192 + uj];
            c1 = fmaf(fv, c1, iv * gv);
            h1buf[ubb][uj] = ov * tanh_fast(c1);
        }
        __syncthreads();

        // ---------------- layer 2 gates ----------------
#pragma unroll
        for (int b = 0; b < NB; ++b) {
            const float4* h1v = (const float4*)h1buf[b];
            const float4* h2v = (const float4*)h2buf[b];
            float a = bias1;
#pragma unroll
            for (int k4 = 0; k4 < 16; ++k4) {
                float4 h1 = h1v[k4];
                a = fmaf(wih1[4*k4+0], h1.x, a);
                a = fmaf(wih1[4*k4+1], h1.y, a);
                a = fmaf(wih1[4*k4+2], h1.z, a);
                a = fmaf(wih1[4*k4+3], h1.w, a);
                float4 h2 = h2v[k4];
                a = fmaf(whh1[4*k4+0], h2.x, a);
                a = fmaf(whh1[4*k4+1], h2.y, a);
                a = fmaf(whh1[4*k4+2], h2.z, a);
                a = fmaf(whh1[4*k4+3], h2.w, a);
            }
            acc[b] = a;
        }
#pragma unroll
        for (int b = 0; b < NB; ++b)
            gbuf[b][g] = (typ == 2) ? tanh_fast(acc[b]) : sigf(acc[b]);
        __syncthreads();

        // ---------------- layer 2 cell/hidden update ----------------
        if (g < NB * 64) {
            const float iv = gbuf[ubb][uj];
            const float fv = gbuf[ubb][64 + uj];
            const float gv = gbuf[ubb][128 + uj];
            const float ov = gbuf[ubb][192 + uj];
            c2 = fmaf(fv, c2, iv * gv);
            h2buf[ubb][uj] = ov * tanh_fast(c2);
        }
        __syncthreads();

#pragma unroll
        for (int b = 0; b < NB; ++b)
#pragma unroll
            for (int d = 0; d < INPUT_D; ++d) xcur[b][d] = xnxt[b][d];
    }

    // ---------------- FC head on h2[t=511] ----------------
    if (g < NB * 32) {
        const int bb = g >> 5, u = g & 31;
        const float4* wv = (const float4*)(W_fc1 + u * 64);
        const float4* hv = (const float4*)h2buf[bb];
        float a = b_fc1[u];
#pragma unroll
        for (int k4 = 0; k4 < 16; ++k4) {
            float4 w = wv[k4];
            float4 h = hv[k4];
            a = fmaf(w.x, h.x, a);
            a = fmaf(w.y, h.y, a);
            a = fmaf(w.z, h.z, a);
            a = fmaf(w.w, h.w, a);
        }
        fcbuf[bb][u] = fmaxf(a, 0.0f);
    }
    __syncthreads();
    if (g < NB) {
        float a = b_fc2[0];
#pragma unroll
        for (int k = 0; k < 32; ++k) a = fmaf(W_fc2[k], fcbuf[g][k], a);
        out[b0 + g] = a;
    }
}

extern "C" void kernel_launch(void* const* d_in, const int* in_sizes, int n_in,
                              void* d_out, int out_size, void* d_ws, size_t ws_size,
                              hipStream_t stream) {
    const float* x     = (const float*)d_in[0];
    const float* W_ih0 = (const float*)d_in[1];
    const float* W_hh0 = (const float*)d_in[2];
    const float* b_ih0 = (const float*)d_in[3];
    const float* b_hh0 = (const float*)d_in[4];
    const float* W_ih1 = (const float*)d_in[5];
    const float* W_hh1 = (const float*)d_in[6];
    const float* b_ih1 = (const float*)d_in[7];
    const float* b_hh1 = (const float*)d_in[8];
    const float* W_fc1 = (const float*)d_in[9];
    const float* b_fc1 = (const float*)d_in[10];
    const float* W_fc2 = (const float*)d_in[11];
    const float* b_fc2 = (const float*)d_in[12];
    float* out = (float*)d_out;

    const int B = in_sizes[0] / (TSTEPS * INPUT_D);   // 1024
    lstm_fused_kernel<<<B / NB, 256, 0, stream>>>(
        x, W_ih0, W_hh0, b_ih0, b_hh0,
        W_ih1, W_hh1, b_ih1, b_hh1,
        W_fc1, b_fc1, W_fc2, b_fc2, out);
}

// Round 3
// 7792.430 us; speedup vs baseline: 1.0138x; 1.0138x over previous
//
#include <hip/hip_runtime.h>

#define TSTEPS 512
#define NB 2

__device__ __forceinline__ float sigf(float x) {
    return 1.0f / (1.0f + __expf(-x));
}
__device__ __forceinline__ float tanh_fast(float x) {
    // 1 - 2/(exp(2x)+1); saturates correctly at +/-inf
    return 1.0f - 2.0f / (__expf(2.0f * x) + 1.0f);
}

// 512 threads: thread = (row 0..255, half 0..1). Each thread owns a 32-wide
// k-slice of W_hh0/W_ih1/W_hh1 row -> 96 weight VGPRs. Pair (2*row, 2*row+1)
// combines partial dot products with shfl_xor(1). launch_bounds(512,4)
// caps VGPRs at 128 => 16 waves/CU => 2 WGs/CU => whole grid co-resident.
__global__ __launch_bounds__(512, 4)
void lstm_fused_kernel(const float* __restrict__ x,
                       const float* __restrict__ W_ih0, const float* __restrict__ W_hh0,
                       const float* __restrict__ b_ih0, const float* __restrict__ b_hh0,
                       const float* __restrict__ W_ih1, const float* __restrict__ W_hh1,
                       const float* __restrict__ b_ih1, const float* __restrict__ b_hh1,
                       const float* __restrict__ W_fc1, const float* __restrict__ b_fc1,
                       const float* __restrict__ W_fc2, const float* __restrict__ b_fc2,
                       float* __restrict__ out)
{
    const int tid  = threadIdx.x;
    const int row  = tid >> 1;        // gate row 0..255
    const int half = tid & 1;         // which 32-wide k-slice
    const int kb   = half << 5;       // 0 or 32
    const int b0   = blockIdx.x * NB;
    const int typ  = row >> 6;        // 0=i 1=f 2=g 3=o (wave-uniform: wave covers 32 rows)

    // ------------- per-thread weight slices (96 VGPRs) -------------
    float whh0[32], wih1[32], whh1[32];
    {
        const float4* p0 = (const float4*)(W_hh0 + row * 64 + kb);
        const float4* p1 = (const float4*)(W_ih1 + row * 64 + kb);
        const float4* p2 = (const float4*)(W_hh1 + row * 64 + kb);
#pragma unroll
        for (int k4 = 0; k4 < 8; ++k4) {
            float4 a = p0[k4];
            whh0[4*k4+0]=a.x; whh0[4*k4+1]=a.y; whh0[4*k4+2]=a.z; whh0[4*k4+3]=a.w;
            float4 b = p1[k4];
            wih1[4*k4+0]=b.x; wih1[4*k4+1]=b.y; wih1[4*k4+2]=b.z; wih1[4*k4+3]=b.w;
            float4 c = p2[k4];
            whh1[4*k4+0]=c.x; whh1[4*k4+1]=c.y; whh1[4*k4+2]=c.z; whh1[4*k4+3]=c.w;
        }
    }
    float wih0[6] = {0.f,0.f,0.f,0.f,0.f,0.f};
    float bias0 = 0.f, bias1 = 0.f;
    if (half == 0) {   // x-projection + biases handled once per row by half 0
#pragma unroll
        for (int d = 0; d < 6; ++d) wih0[d] = W_ih0[row * 6 + d];
        bias0 = b_ih0[row] + b_hh0[row];
        bias1 = b_ih1[row] + b_hh1[row];
    }

    // ------------- LDS -------------
    __shared__ __align__(16) float xl[NB][TSTEPS][8];   // x staged, padded to 8
    __shared__ __align__(16) float h1buf[NB][64];
    __shared__ __align__(16) float h2buf[NB][64];
    __shared__ float gA[NB][256];                       // layer-1 gates
    __shared__ float gB[NB][256];                       // layer-2 gates
    __shared__ float fcbuf[NB][32];

    // stage x: 512 threads <-> 512 timesteps, 6 floats each (3x float2)
#pragma unroll
    for (int b = 0; b < NB; ++b) {
        const float2* src = (const float2*)(x + ((size_t)(b0 + b) * TSTEPS + tid) * 6);
        float2 a0 = src[0], a1 = src[1], a2 = src[2];
        float2* dst = (float2*)&xl[b][tid][0];
        dst[0] = a0; dst[1] = a1; dst[2] = a2;
    }
    if (tid < NB * 64) {
        h1buf[tid >> 6][tid & 63] = 0.f;
        h2buf[tid >> 6][tid & 63] = 0.f;
    }
    float c = 0.f;   // c1 for tid<128 (P2), c2 for tid in [128,256) (P4)
    __syncthreads();

    for (int t = 0; t < TSTEPS; ++t) {
        float acc[NB];
        // ---- P1: layer-1 gate partials ----
#pragma unroll
        for (int b = 0; b < NB; ++b) {
            float a = 0.f;
            const float4* hv = (const float4*)&h1buf[b][kb];
#pragma unroll
            for (int k4 = 0; k4 < 8; ++k4) {
                float4 h = hv[k4];
                a = fmaf(whh0[4*k4+0], h.x, a);
                a = fmaf(whh0[4*k4+1], h.y, a);
                a = fmaf(whh0[4*k4+2], h.z, a);
                a = fmaf(whh0[4*k4+3], h.w, a);
            }
            if (half == 0) {
                const float4 xv = *(const float4*)&xl[b][t][0];
                const float2 xw = *(const float2*)&xl[b][t][4];
                a += bias0;
                a = fmaf(wih0[0], xv.x, a);
                a = fmaf(wih0[1], xv.y, a);
                a = fmaf(wih0[2], xv.z, a);
                a = fmaf(wih0[3], xv.w, a);
                a = fmaf(wih0[4], xw.x, a);
                a = fmaf(wih0[5], xw.y, a);
            }
            acc[b] = a;
        }
#pragma unroll
        for (int b = 0; b < NB; ++b) {
            float s = acc[b] + __shfl_xor(acc[b], 1, 64);
            if (half == 0) gA[b][row] = (typ == 2) ? tanh_fast(s) : sigf(s);
        }
        __syncthreads();

        // ---- P2: layer-1 cell/hidden update (waves 0-1) ----
        if (tid < NB * 64) {
            const int bb = tid >> 6, j = tid & 63;
            const float iv = gA[bb][j];
            const float fv = gA[bb][64 + j];
            const float gv = gA[bb][128 + j];
            const float ov = gA[bb][192 + j];
            c = fmaf(fv, c, iv * gv);
            h1buf[bb][j] = ov * tanh_fast(c);
        }
        __syncthreads();

        // ---- P3: layer-2 gate partials ----
#pragma unroll
        for (int b = 0; b < NB; ++b) {
            float a = (half == 0) ? bias1 : 0.f;
            const float4* h1v = (const float4*)&h1buf[b][kb];
            const float4* h2v = (const float4*)&h2buf[b][kb];
#pragma unroll
            for (int k4 = 0; k4 < 8; ++k4) {
                float4 h1 = h1v[k4];
                a = fmaf(wih1[4*k4+0], h1.x, a);
                a = fmaf(wih1[4*k4+1], h1.y, a);
                a = fmaf(wih1[4*k4+2], h1.z, a);
                a = fmaf(wih1[4*k4+3], h1.w, a);
                float4 h2 = h2v[k4];
                a = fmaf(whh1[4*k4+0], h2.x, a);
                a = fmaf(whh1[4*k4+1], h2.y, a);
                a = fmaf(whh1[4*k4+2], h2.z, a);
                a = fmaf(whh1[4*k4+3], h2.w, a);
            }
            acc[b] = a;
        }
#pragma unroll
        for (int b = 0; b < NB; ++b) {
            float s = acc[b] + __shfl_xor(acc[b], 1, 64);
            if (half == 0) gB[b][row] = (typ == 2) ? tanh_fast(s) : sigf(s);
        }
        __syncthreads();

        // ---- P4: layer-2 cell/hidden update (waves 2-3); no trailing barrier:
        // h2buf is next read in P3' (two barriers away), gB next written in P3'.
        if (tid >= 128 && tid < 128 + NB * 64) {
            const int u = tid - 128;
            const int bb = u >> 6, j = u & 63;
            const float iv = gB[bb][j];
            const float fv = gB[bb][64 + j];
            const float gv = gB[bb][128 + j];
            const float ov = gB[bb][192 + j];
            c = fmaf(fv, c, iv * gv);
            h2buf[bb][j] = ov * tanh_fast(c);
        }
    }
    __syncthreads();

    // ---- FC head on h2[t=511] ----
    if (tid < NB * 32) {
        const int bb = tid >> 5, u = tid & 31;
        const float4* wv = (const float4*)(W_fc1 + u * 64);
        const float4* hv = (const float4*)h2buf[bb];
        float a = b_fc1[u];
#pragma unroll
        for (int k4 = 0; k4 < 16; ++k4) {
            float4 w = wv[k4];
            float4 h = hv[k4];
            a = fmaf(w.x, h.x, a);
            a = fmaf(w.y, h.y, a);
            a = fmaf(w.z, h.z, a);
            a = fmaf(w.w, h.w, a);
        }
        fcbuf[bb][u] = fmaxf(a, 0.0f);
    }
    __syncthreads();
    if (tid < NB) {
        float a = b_fc2[0];
#pragma unroll
        for (int k = 0; k < 32; ++k) a = fmaf(W_fc2[k], fcbuf[tid][k], a);
        out[b0 + tid] = a;
    }
}

extern "C" void kernel_launch(void* const* d_in, const int* in_sizes, int n_in,
                              void* d_out, int out_size, void* d_ws, size_t ws_size,
                              hipStream_t stream) {
    const float* x     = (const float*)d_in[0];
    const float* W_ih0 = (const float*)d_in[1];
    const float* W_hh0 = (const float*)d_in[2];
    const float* b_ih0 = (const float*)d_in[3];
    const float* b_hh0 = (const float*)d_in[4];
    const float* W_ih1 = (const float*)d_in[5];
    const float* W_hh1 = (const float*)d_in[6];
    const float* b_ih1 = (const float*)d_in[7];
    const float* b_hh1 = (const float*)d_in[8];
    const float* W_fc1 = (const float*)d_in[9];
    const float* b_fc1 = (const float*)d_in[10];
    const float* W_fc2 = (const float*)d_in[11];
    const float* b_fc2 = (const float*)d_in[12];
    float* out = (float*)d_out;

    const int B = in_sizes[0] / (TSTEPS * 6);   // 1024
    lstm_fused_kernel<<<B / NB, 512, 0, stream>>>(
        x, W_ih0, W_hh0, b_ih0, b_hh0,
        W_ih1, W_hh1, b_ih1, b_hh1,
        W_fc1, b_fc1, W_fc2, b_fc2, out);
}

// Round 4
// 7750.821 us; speedup vs baseline: 1.0192x; 1.0054x over previous
//
#include <hip/hip_runtime.h>

#define TSTEPS 512
#define NB 2

__device__ __forceinline__ float sigf(float x) {
    return 1.0f / (1.0f + __expf(-x));
}
__device__ __forceinline__ float tanh_fast(float x) {
    // 1 - 2/(exp(2x)+1); saturates correctly at +/-inf
    return 1.0f - 2.0f / (__expf(2.0f * x) + 1.0f);
}

// 512 threads: thread = (row 0..255, half 0..1). Each thread owns a 32-wide
// k-slice of W_hh0/W_ih1/W_hh1 row -> 96 weight VGPRs. Pair (2*row, 2*row+1)
// combines partial dot products with shfl_xor(1).
// amdgpu_waves_per_eu(4,4) PINS the allocator at 4 waves/EU (128 VGPR cap):
// round-2/3 showed launch_bounds' 2nd arg is only a minimum — the backend
// targeted 8 waves/EU, allocated 64 VGPR, and spilled all weights to scratch
// (FETCH_SIZE 16.5 GB of spill re-reads).
__global__
__attribute__((amdgpu_flat_work_group_size(512, 512), amdgpu_waves_per_eu(4, 4)))
void lstm_fused_kernel(const float* __restrict__ x,
                       const float* __restrict__ W_ih0, const float* __restrict__ W_hh0,
                       const float* __restrict__ b_ih0, const float* __restrict__ b_hh0,
                       const float* __restrict__ W_ih1, const float* __restrict__ W_hh1,
                       const float* __restrict__ b_ih1, const float* __restrict__ b_hh1,
                       const float* __restrict__ W_fc1, const float* __restrict__ b_fc1,
                       const float* __restrict__ W_fc2, const float* __restrict__ b_fc2,
                       float* __restrict__ out)
{
    const int tid  = threadIdx.x;
    const int row  = tid >> 1;        // gate row 0..255
    const int half = tid & 1;         // which 32-wide k-slice
    const int kb   = half << 5;       // 0 or 32
    const int b0   = blockIdx.x * NB;
    const int typ  = row >> 6;        // 0=i 1=f 2=g 3=o (wave-uniform: wave covers 32 rows)

    // ------------- per-thread weight slices (96 VGPRs) -------------
    float whh0[32], wih1[32], whh1[32];
    {
        const float4* p0 = (const float4*)(W_hh0 + row * 64 + kb);
        const float4* p1 = (const float4*)(W_ih1 + row * 64 + kb);
        const float4* p2 = (const float4*)(W_hh1 + row * 64 + kb);
#pragma unroll
        for (int k4 = 0; k4 < 8; ++k4) {
            float4 a = p0[k4];
            whh0[4*k4+0]=a.x; whh0[4*k4+1]=a.y; whh0[4*k4+2]=a.z; whh0[4*k4+3]=a.w;
            float4 b = p1[k4];
            wih1[4*k4+0]=b.x; wih1[4*k4+1]=b.y; wih1[4*k4+2]=b.z; wih1[4*k4+3]=b.w;
            float4 c = p2[k4];
            whh1[4*k4+0]=c.x; whh1[4*k4+1]=c.y; whh1[4*k4+2]=c.z; whh1[4*k4+3]=c.w;
        }
    }
    float wih0[6] = {0.f,0.f,0.f,0.f,0.f,0.f};
    float bias0 = 0.f, bias1 = 0.f;
    if (half == 0) {   // x-projection + biases handled once per row by half 0
#pragma unroll
        for (int d = 0; d < 6; ++d) wih0[d] = W_ih0[row * 6 + d];
        bias0 = b_ih0[row] + b_hh0[row];
        bias1 = b_ih1[row] + b_hh1[row];
    }

    // ------------- LDS -------------
    __shared__ __align__(16) float xl[NB][TSTEPS][8];   // x staged, padded to 8
    __shared__ __align__(16) float h1buf[NB][64];
    __shared__ __align__(16) float h2buf[NB][64];
    __shared__ float gA[NB][256];                       // layer-1 gates
    __shared__ float gB[NB][256];                       // layer-2 gates
    __shared__ float fcbuf[NB][32];

    // stage x: 512 threads <-> 512 timesteps, 6 floats each (3x float2)
#pragma unroll
    for (int b = 0; b < NB; ++b) {
        const float2* src = (const float2*)(x + ((size_t)(b0 + b) * TSTEPS + tid) * 6);
        float2 a0 = src[0], a1 = src[1], a2 = src[2];
        float2* dst = (float2*)&xl[b][tid][0];
        dst[0] = a0; dst[1] = a1; dst[2] = a2;
    }
    if (tid < NB * 64) {
        h1buf[tid >> 6][tid & 63] = 0.f;
        h2buf[tid >> 6][tid & 63] = 0.f;
    }
    float c = 0.f;   // c1 for tid<128 (P2), c2 for tid in [128,256) (P4)
    __syncthreads();

    for (int t = 0; t < TSTEPS; ++t) {
        float acc[NB];
        // ---- P1: layer-1 gate partials ----
#pragma unroll
        for (int b = 0; b < NB; ++b) {
            float a = 0.f;
            const float4* hv = (const float4*)&h1buf[b][kb];
#pragma unroll
            for (int k4 = 0; k4 < 8; ++k4) {
                float4 h = hv[k4];
                a = fmaf(whh0[4*k4+0], h.x, a);
                a = fmaf(whh0[4*k4+1], h.y, a);
                a = fmaf(whh0[4*k4+2], h.z, a);
                a = fmaf(whh0[4*k4+3], h.w, a);
            }
            if (half == 0) {
                const float4 xv = *(const float4*)&xl[b][t][0];
                const float2 xw = *(const float2*)&xl[b][t][4];
                a += bias0;
                a = fmaf(wih0[0], xv.x, a);
                a = fmaf(wih0[1], xv.y, a);
                a = fmaf(wih0[2], xv.z, a);
                a = fmaf(wih0[3], xv.w, a);
                a = fmaf(wih0[4], xw.x, a);
                a = fmaf(wih0[5], xw.y, a);
            }
            acc[b] = a;
        }
#pragma unroll
        for (int b = 0; b < NB; ++b) {
            float s = acc[b] + __shfl_xor(acc[b], 1, 64);
            if (half == 0) gA[b][row] = (typ == 2) ? tanh_fast(s) : sigf(s);
        }
        __syncthreads();

        // ---- P2: layer-1 cell/hidden update (waves 0-1) ----
        if (tid < NB * 64) {
            const int bb = tid >> 6, j = tid & 63;
            const float iv = gA[bb][j];
            const float fv = gA[bb][64 + j];
            const float gv = gA[bb][128 + j];
            const float ov = gA[bb][192 + j];
            c = fmaf(fv, c, iv * gv);
            h1buf[bb][j] = ov * tanh_fast(c);
        }
        __syncthreads();

        // ---- P3: layer-2 gate partials ----
#pragma unroll
        for (int b = 0; b < NB; ++b) {
            float a = (half == 0) ? bias1 : 0.f;
            const float4* h1v = (const float4*)&h1buf[b][kb];
            const float4* h2v = (const float4*)&h2buf[b][kb];
#pragma unroll
            for (int k4 = 0; k4 < 8; ++k4) {
                float4 h1 = h1v[k4];
                a = fmaf(wih1[4*k4+0], h1.x, a);
                a = fmaf(wih1[4*k4+1], h1.y, a);
                a = fmaf(wih1[4*k4+2], h1.z, a);
                a = fmaf(wih1[4*k4+3], h1.w, a);
                float4 h2 = h2v[k4];
                a = fmaf(whh1[4*k4+0], h2.x, a);
                a = fmaf(whh1[4*k4+1], h2.y, a);
                a = fmaf(whh1[4*k4+2], h2.z, a);
                a = fmaf(whh1[4*k4+3], h2.w, a);
            }
            acc[b] = a;
        }
#pragma unroll
        for (int b = 0; b < NB; ++b) {
            float s = acc[b] + __shfl_xor(acc[b], 1, 64);
            if (half == 0) gB[b][row] = (typ == 2) ? tanh_fast(s) : sigf(s);
        }
        __syncthreads();

        // ---- P4: layer-2 cell/hidden update (waves 2-3); no trailing barrier:
        // h2buf is next read in P3' (two barriers away), gB next written in P3'.
        if (tid >= 128 && tid < 128 + NB * 64) {
            const int u = tid - 128;
            const int bb = u >> 6, j = u & 63;
            const float iv = gB[bb][j];
            const float fv = gB[bb][64 + j];
            const float gv = gB[bb][128 + j];
            const float ov = gB[bb][192 + j];
            c = fmaf(fv, c, iv * gv);
            h2buf[bb][j] = ov * tanh_fast(c);
        }
    }
    __syncthreads();

    // ---- FC head on h2[t=511] ----
    if (tid < NB * 32) {
        const int bb = tid >> 5, u = tid & 31;
        const float4* wv = (const float4*)(W_fc1 + u * 64);
        const float4* hv = (const float4*)h2buf[bb];
        float a = b_fc1[u];
#pragma unroll
        for (int k4 = 0; k4 < 16; ++k4) {
            float4 w = wv[k4];
            float4 h = hv[k4];
            a = fmaf(w.x, h.x, a);
            a = fmaf(w.y, h.y, a);
            a = fmaf(w.z, h.z, a);
            a = fmaf(w.w, h.w, a);
        }
        fcbuf[bb][u] = fmaxf(a, 0.0f);
    }
    __syncthreads();
    if (tid < NB) {
        float a = b_fc2[0];
#pragma unroll
        for (int k = 0; k < 32; ++k) a = fmaf(W_fc2[k], fcbuf[tid][k], a);
        out[b0 + tid] = a;
    }
}

extern "C" void kernel_launch(void* const* d_in, const int* in_sizes, int n_in,
                              void* d_out, int out_size, void* d_ws, size_t ws_size,
                              hipStream_t stream) {
    const float* x     = (const float*)d_in[0];
    const float* W_ih0 = (const float*)d_in[1];
    const float* W_hh0 = (const float*)d_in[2];
    const float* b_ih0 = (const float*)d_in[3];
    const float* b_hh0 = (const float*)d_in[4];
    const float* W_ih1 = (const float*)d_in[5];
    const float* W_hh1 = (const float*)d_in[6];
    const float* b_ih1 = (const float*)d_in[7];
    const float* b_hh1 = (const float*)d_in[8];
    const float* W_fc1 = (const float*)d_in[9];
    const float* b_fc1 = (const float*)d_in[10];
    const float* W_fc2 = (const float*)d_in[11];
    const float* b_fc2 = (const float*)d_in[12];
    float* out = (float*)d_out;

    const int B = in_sizes[0] / (TSTEPS * 6);   // 1024
    lstm_fused_kernel<<<B / NB, 512, 0, stream>>>(
        x, W_ih0, W_hh0, b_ih0, b_hh0,
        W_ih1, W_hh1, b_ih1, b_hh1,
        W_fc1, b_fc1, W_fc2, b_fc2, out);
}

// Round 5
// 1925.187 us; speedup vs baseline: 4.1033x; 4.0260x over previous
//
#include <hip/hip_runtime.h>

#define TSTEPS 512
#define NB 2

__device__ __forceinline__ float sigf(float x) {
    return 1.0f / (1.0f + __expf(-x));
}
__device__ __forceinline__ float tanh_fast(float x) {
    return 1.0f - 2.0f / (__expf(2.0f * x) + 1.0f);
}

__device__ __forceinline__ float dot16(float4 wa, float4 wb, float4 wc, float4 wd,
                                       float4 h0, float4 h1, float4 h2, float4 h3,
                                       float a) {
    a = fmaf(wa.x, h0.x, a); a = fmaf(wa.y, h0.y, a);
    a = fmaf(wa.z, h0.z, a); a = fmaf(wa.w, h0.w, a);
    a = fmaf(wb.x, h1.x, a); a = fmaf(wb.y, h1.y, a);
    a = fmaf(wb.z, h1.z, a); a = fmaf(wb.w, h1.w, a);
    a = fmaf(wc.x, h2.x, a); a = fmaf(wc.y, h2.y, a);
    a = fmaf(wc.z, h2.z, a); a = fmaf(wc.w, h2.w, a);
    a = fmaf(wd.x, h3.x, a); a = fmaf(wd.y, h3.y, a);
    a = fmaf(wd.z, h3.z, a); a = fmaf(wd.w, h3.w, a);
    return a;
}

// 1024 threads: thread = (row r 0..255, quarter q 0..3). Each thread owns a
// 16-wide k-slice of W_hh0/W_ih1/W_hh1 row as 12 explicit float4 registers
// (48 VGPRs). Demand ~64 total => spill-free under the allocator's worst
// observed grant (64 VGPRs at 8 waves/EU), which rounds 2-4 showed we cannot
// override. 4-thread shfl_xor butterfly combines k-slice partials.
// x-projection+bias precomputed into xg[] by waves 8-15 during the update
// phase (zero hot-path registers).
__global__ __launch_bounds__(1024)
void lstm_fused_kernel(const float* __restrict__ x,
                       const float* __restrict__ W_ih0, const float* __restrict__ W_hh0,
                       const float* __restrict__ b_ih0, const float* __restrict__ b_hh0,
                       const float* __restrict__ W_ih1, const float* __restrict__ W_hh1,
                       const float* __restrict__ b_ih1, const float* __restrict__ b_hh1,
                       const float* __restrict__ W_fc1, const float* __restrict__ b_fc1,
                       const float* __restrict__ W_fc2, const float* __restrict__ b_fc2,
                       float* __restrict__ out)
{
    const int tid = threadIdx.x;
    const int r   = tid >> 2;         // gate row 0..255
    const int q   = tid & 3;          // k-quarter
    const int kb  = q << 4;           // 0,16,32,48
    const int b0  = blockIdx.x * NB;
    const int typ = r >> 6;           // 0=i 1=f 2=g 3=o

    // ---- weight slices: 12 explicit float4 (48 VGPRs), no arrays ----
    const float4* p0 = (const float4*)(W_hh0 + r * 64 + kb);
    const float4* p1 = (const float4*)(W_ih1 + r * 64 + kb);
    const float4* p2 = (const float4*)(W_hh1 + r * 64 + kb);
    const float4 wA0 = p0[0], wA1 = p0[1], wA2 = p0[2], wA3 = p0[3];
    const float4 wB0 = p1[0], wB1 = p1[1], wB2 = p1[2], wB3 = p1[3];
    const float4 wC0 = p2[0], wC1 = p2[1], wC2 = p2[2], wC3 = p2[3];

    // ---- LDS ----
    __shared__ __align__(16) float xl[NB][TSTEPS][6];   // staged x
    __shared__ float wih0s[6][256];                     // W_ih0 transposed
    __shared__ float bias0s[256], bias1s[256];
    __shared__ float xg[NB][256];                       // bias0 + W_ih0 @ x_t
    __shared__ float gA[NB][256], gB[NB][256];          // activated gates
    __shared__ __align__(16) float h1buf[NB][64], h2buf[NB][64];
    __shared__ float fcbuf[NB][32];

    // stage x: 1024 threads <-> (b, t) pairs
    {
        const int sb = tid >> 9, st = tid & 511;
        const float2* src = (const float2*)(x + ((size_t)(b0 + sb) * TSTEPS + st) * 6);
        float2 a0 = src[0], a1 = src[1], a2 = src[2];
        float2* dst = (float2*)&xl[sb][st][0];
        dst[0] = a0; dst[1] = a1; dst[2] = a2;
    }
    if (tid < 256) {
        bias0s[tid] = b_ih0[tid] + b_hh0[tid];
        bias1s[tid] = b_ih1[tid] + b_hh1[tid];
#pragma unroll
        for (int d = 0; d < 6; ++d) wih0s[d][tid] = W_ih0[tid * 6 + d];
    }
    if (tid < NB * 64) {
        h1buf[tid >> 6][tid & 63] = 0.f;
        h2buf[tid >> 6][tid & 63] = 0.f;
    }
    float c = 0.f;   // c1 for tid<128, c2 for tid in [128,256)
    __syncthreads();

    // xg for t=0 (waves 8-15)
    if (tid >= 512) {
        const int u = tid - 512, bb = u >> 8, rr = u & 255;
        float a = bias0s[rr];
#pragma unroll
        for (int d = 0; d < 6; ++d) a = fmaf(wih0s[d][rr], xl[bb][0][d], a);
        xg[bb][rr] = a;
    }
    __syncthreads();

    for (int t = 0; t < TSTEPS; ++t) {
        // ---- P1: layer-1 gates ----
#pragma unroll
        for (int b = 0; b < NB; ++b) {
            const float4* hv = (const float4*)&h1buf[b][kb];
            float4 h0 = hv[0], h1 = hv[1], h2 = hv[2], h3 = hv[3];
            float a = dot16(wA0, wA1, wA2, wA3, h0, h1, h2, h3, 0.f);
            float s = a + __shfl_xor(a, 1, 64);
            s += __shfl_xor(s, 2, 64);
            s += xg[b][r];
            float g = (typ == 2) ? tanh_fast(s) : sigf(s);
            if (q == 0) gA[b][r] = g;
        }
        __syncthreads();   // bar1

        // ---- P2: layer-1 update (waves 0-1) || xg(t+1) (waves 8-15) ----
        if (tid < 128) {
            const int bb = tid >> 6, j = tid & 63;
            const float iv = gA[bb][j];
            const float fv = gA[bb][64 + j];
            const float gv = gA[bb][128 + j];
            const float ov = gA[bb][192 + j];
            c = fmaf(fv, c, iv * gv);
            h1buf[bb][j] = ov * tanh_fast(c);
        } else if (tid >= 512) {
            const int u = tid - 512, bb = u >> 8, rr = u & 255;
            const int tn = (t + 1 < TSTEPS) ? (t + 1) : (TSTEPS - 1);
            float a = bias0s[rr];
#pragma unroll
            for (int d = 0; d < 6; ++d) a = fmaf(wih0s[d][rr], xl[bb][tn][d], a);
            xg[bb][rr] = a;
        }
        __syncthreads();   // bar2

        // ---- P3: layer-2 gates ----
#pragma unroll
        for (int b = 0; b < NB; ++b) {
            const float4* h1v = (const float4*)&h1buf[b][kb];
            const float4* h2v = (const float4*)&h2buf[b][kb];
            float4 u0 = h1v[0], u1 = h1v[1], u2 = h1v[2], u3 = h1v[3];
            float4 v0 = h2v[0], v1 = h2v[1], v2 = h2v[2], v3 = h2v[3];
            float a = dot16(wB0, wB1, wB2, wB3, u0, u1, u2, u3, 0.f);
            a = dot16(wC0, wC1, wC2, wC3, v0, v1, v2, v3, a);
            float s = a + __shfl_xor(a, 1, 64);
            s += __shfl_xor(s, 2, 64);
            s += bias1s[r];
            float g = (typ == 2) ? tanh_fast(s) : sigf(s);
            if (q == 0) gB[b][r] = g;
        }
        __syncthreads();   // bar3

        // ---- P4: layer-2 update (waves 2-3); no trailing barrier:
        // h2buf next read in P3(t+1) (2 barriers away); gB next written in
        // P3(t+1) (after bar2(t+1), by when P4(t) threads passed bar1(t+1)).
        if (tid >= 128 && tid < 256) {
            const int u = tid - 128, bb = u >> 6, j = u & 63;
            const float iv = gB[bb][j];
            const float fv = gB[bb][64 + j];
            const float gv = gB[bb][128 + j];
            const float ov = gB[bb][192 + j];
            c = fmaf(fv, c, iv * gv);
            h2buf[bb][j] = ov * tanh_fast(c);
        }
    }
    __syncthreads();

    // ---- FC head on h2[t=511] ----
    if (tid < NB * 32) {
        const int bb = tid >> 5, u = tid & 31;
        const float4* wv = (const float4*)(W_fc1 + u * 64);
        const float4* hv = (const float4*)h2buf[bb];
        float a = b_fc1[u];
#pragma unroll
        for (int k4 = 0; k4 < 16; ++k4) {
            float4 w = wv[k4];
            float4 h = hv[k4];
            a = fmaf(w.x, h.x, a);
            a = fmaf(w.y, h.y, a);
            a = fmaf(w.z, h.z, a);
            a = fmaf(w.w, h.w, a);
        }
        fcbuf[bb][u] = fmaxf(a, 0.0f);
    }
    __syncthreads();
    if (tid < NB) {
        float a = b_fc2[0];
#pragma unroll
        for (int k = 0; k < 32; ++k) a = fmaf(W_fc2[k], fcbuf[tid][k], a);
        out[b0 + tid] = a;
    }
}

extern "C" void kernel_launch(void* const* d_in, const int* in_sizes, int n_in,
                              void* d_out, int out_size, void* d_ws, size_t ws_size,
                              hipStream_t stream) {
    const float* x     = (const float*)d_in[0];
    const float* W_ih0 = (const float*)d_in[1];
    const float* W_hh0 = (const float*)d_in[2];
    const float* b_ih0 = (const float*)d_in[3];
    const float* b_hh0 = (const float*)d_in[4];
    const float* W_ih1 = (const float*)d_in[5];
    const float* W_hh1 = (const float*)d_in[6];
    const float* b_ih1 = (const float*)d_in[7];
    const float* b_hh1 = (const float*)d_in[8];
    const float* W_fc1 = (const float*)d_in[9];
    const float* b_fc1 = (const float*)d_in[10];
    const float* W_fc2 = (const float*)d_in[11];
    const float* b_fc2 = (const float*)d_in[12];
    float* out = (float*)d_out;

    const int B = in_sizes[0] / (TSTEPS * 6);   // 1024
    lstm_fused_kernel<<<B / NB, 1024, 0, stream>>>(
        x, W_ih0, W_hh0, b_ih0, b_hh0,
        W_ih1, W_hh1, b_ih1, b_hh1,
        W_fc1, b_fc1, W_fc2, b_fc2, out);
}

// Round 6
// 905.453 us; speedup vs baseline: 8.7246x; 2.1262x over previous
//
#include <hip/hip_runtime.h>

#define T_STEPS 512
#define HPAD 76   // LDS row pad (floats): 16B-aligned rows, ~2-way bank conflicts

typedef _Float16 half8 __attribute__((ext_vector_type(8)));
typedef float f32x4 __attribute__((ext_vector_type(4)));

__device__ __forceinline__ float sigf(float v) { return 1.0f / (1.0f + __expf(-v)); }
__device__ __forceinline__ float tanh_fast(float v) { return 1.0f - 2.0f / (__expf(2.0f * v) + 1.0f); }

// 8 floats -> 8 fp16 (RTN via scalar casts)
__device__ __forceinline__ half8 pack8(f32x4 a, f32x4 b) {
    half8 r;
    r[0] = (_Float16)a[0]; r[1] = (_Float16)a[1];
    r[2] = (_Float16)a[2]; r[3] = (_Float16)a[3];
    r[4] = (_Float16)b[0]; r[5] = (_Float16)b[1];
    r[6] = (_Float16)b[2]; r[7] = (_Float16)b[3];
    return r;
}

// MFMA fragment maps (16x16x32, m89/m92-verified family):
//   A[16xK32]: row = lane&15, k = (lane>>4)*8 + i   (8 consecutive, 4 VGPR)
//   B[K32x16]: col = lane&15, k = (lane>>4)*8 + i
//   D[16x16] : col = lane&15, row = (lane>>4)*4 + reg
// WG = 16 batch rows (M=16). Waves 0-3: layer1; waves 4-7: layer2 (pipelined
// one step behind). Wave lw owns j in [16lw,16lw+16) via col-tiles
// {lw, lw+4, lw+8, lw+12} => per lane the 4 gate types for (batch=4*g4+reg,
// j=16lw+col) sit in 4 accumulators of the SAME lane -> in-register cell update.
// h crosses steps through padded LDS (fp32), re-read as A-fragments + fp16 cvt.
// padlds forces ~83KB LDS -> 1 WG/CU -> 2 waves/EU -> 256-VGPR grant tier
// (rounds 2-5: allocator sizes VGPRs to the LDS-allowed max occupancy).
__global__ __launch_bounds__(512)
void lstm_mfma_kernel(const float* __restrict__ x,
                      const float* __restrict__ W_ih0, const float* __restrict__ W_hh0,
                      const float* __restrict__ b_ih0, const float* __restrict__ b_hh0,
                      const float* __restrict__ W_ih1, const float* __restrict__ W_hh1,
                      const float* __restrict__ b_ih1, const float* __restrict__ b_hh1,
                      const float* __restrict__ W_fc1, const float* __restrict__ b_fc1,
                      const float* __restrict__ W_fc2, const float* __restrict__ b_fc2,
                      float* __restrict__ out)
{
    const int tid  = threadIdx.x;
    const int lane = tid & 63;
    const int wid  = tid >> 6;      // 0..7
    const int lw   = wid & 3;       // wave index within role group
    const bool isL2 = wid >= 4;
    const int b0   = blockIdx.x * 16;
    const int col  = lane & 15;     // B-frag col / A-frag row
    const int g4   = lane >> 4;     // k-group

    __shared__ __align__(16) float h1buf[2][16][HPAD];
    __shared__ __align__(16) float h2buf[2][16][HPAD];
    __shared__ float fcbuf[16][32];
    __shared__ float padlds[15360];   // occupancy shaping only

    if (blockIdx.x == 0x7fffffff) {   // never true at grid=64; keeps padlds live
        padlds[tid] = (float)tid;
        out[0] = padlds[0];
    }

    // ---------------- weight fragments (one-time) ----------------
    // L1 chunks: 0 = x (k0..5 real, rest 0), 1..2 = W_hh0 k-halves
    // L2 chunks: 0..1 = W_ih1 (vs h1), 2..3 = W_hh1 (vs h2)
    half8 wf[4][4];
    float bias[4];
#pragma unroll
    for (int n = 0; n < 4; ++n) {
        const int grow = 16 * (lw + 4 * n) + col;   // gate row of tile n
        if (!isL2) {
            half8 wx;
#pragma unroll
            for (int i = 0; i < 8; ++i) wx[i] = (_Float16)0.f;
            if (g4 == 0) {
                const float2* wp = (const float2*)(W_ih0 + grow * 6);
                float2 w0 = wp[0], w1 = wp[1], w2 = wp[2];
                wx[0] = (_Float16)w0.x; wx[1] = (_Float16)w0.y;
                wx[2] = (_Float16)w1.x; wx[3] = (_Float16)w1.y;
                wx[4] = (_Float16)w2.x; wx[5] = (_Float16)w2.y;
            }
            wf[n][0] = wx;
#pragma unroll
            for (int c = 0; c < 2; ++c) {
                const f32x4* wp = (const f32x4*)(W_hh0 + grow * 64 + 32 * c + 8 * g4);
                wf[n][1 + c] = pack8(wp[0], wp[1]);
            }
            wf[n][3] = wf[n][0];  // unused in L1 path
            bias[n] = b_ih0[grow] + b_hh0[grow];
        } else {
#pragma unroll
            for (int c = 0; c < 2; ++c) {
                const f32x4* wp = (const f32x4*)(W_ih1 + grow * 64 + 32 * c + 8 * g4);
                wf[n][c] = pack8(wp[0], wp[1]);
            }
#pragma unroll
            for (int c = 0; c < 2; ++c) {
                const f32x4* wp = (const f32x4*)(W_hh1 + grow * 64 + 32 * c + 8 * g4);
                wf[n][2 + c] = pack8(wp[0], wp[1]);
            }
            bias[n] = b_ih1[grow] + b_hh1[grow];
        }
    }

    // zero both h double-buffers
    for (int i = tid; i < 2 * 16 * HPAD; i += 512) {
        (&h1buf[0][0][0])[i] = 0.f;
        (&h2buf[0][0][0])[i] = 0.f;
    }

    float cst0 = 0.f, cst1 = 0.f, cst2 = 0.f, cst3 = 0.f;  // cell state (4 batch rows)
    float xr0=0.f, xr1=0.f, xr2=0.f, xr3=0.f, xr4=0.f, xr5=0.f;
    if (!isL2) {   // x(t=0) prefetch; lane's batch = col (dup across g4, L1-cached)
        const float2* xp = (const float2*)(x + (size_t)(b0 + col) * T_STEPS * 6);
        float2 v0 = xp[0], v1 = xp[1], v2 = xp[2];
        xr0 = v0.x; xr1 = v0.y; xr2 = v1.x; xr3 = v1.y; xr4 = v2.x; xr5 = v2.y;
    }
    __syncthreads();

    int p = 0;
    for (int it = 0; it <= T_STEPS; ++it) {
        if (!isL2) {
            if (it < T_STEPS) {   // layer-1 step t = it
                half8 ax;
#pragma unroll
                for (int i = 0; i < 8; ++i) ax[i] = (_Float16)0.f;
                if (g4 == 0) {
                    ax[0] = (_Float16)xr0; ax[1] = (_Float16)xr1; ax[2] = (_Float16)xr2;
                    ax[3] = (_Float16)xr3; ax[4] = (_Float16)xr4; ax[5] = (_Float16)xr5;
                }
                // prefetch next x under this step's compute
                const int tn = (it + 1 < T_STEPS) ? (it + 1) : (T_STEPS - 1);
                const float2* xp = (const float2*)(x + ((size_t)(b0 + col) * T_STEPS + tn) * 6);
                float2 v0 = xp[0], v1 = xp[1], v2 = xp[2];

                const f32x4* h0p = (const f32x4*)&h1buf[p][col][8 * g4];
                const f32x4* h1p = (const f32x4*)&h1buf[p][col][32 + 8 * g4];
                half8 a0 = pack8(h0p[0], h0p[1]);
                half8 a1 = pack8(h1p[0], h1p[1]);

                f32x4 acc0 = {0.f,0.f,0.f,0.f}, acc1 = {0.f,0.f,0.f,0.f};
                f32x4 acc2 = {0.f,0.f,0.f,0.f}, acc3 = {0.f,0.f,0.f,0.f};
                acc0 = __builtin_amdgcn_mfma_f32_16x16x32_f16(ax, wf[0][0], acc0, 0, 0, 0);
                acc1 = __builtin_amdgcn_mfma_f32_16x16x32_f16(ax, wf[1][0], acc1, 0, 0, 0);
                acc2 = __builtin_amdgcn_mfma_f32_16x16x32_f16(ax, wf[2][0], acc2, 0, 0, 0);
                acc3 = __builtin_amdgcn_mfma_f32_16x16x32_f16(ax, wf[3][0], acc3, 0, 0, 0);
                acc0 = __builtin_amdgcn_mfma_f32_16x16x32_f16(a0, wf[0][1], acc0, 0, 0, 0);
                acc1 = __builtin_amdgcn_mfma_f32_16x16x32_f16(a0, wf[1][1], acc1, 0, 0, 0);
                acc2 = __builtin_amdgcn_mfma_f32_16x16x32_f16(a0, wf[2][1], acc2, 0, 0, 0);
                acc3 = __builtin_amdgcn_mfma_f32_16x16x32_f16(a0, wf[3][1], acc3, 0, 0, 0);
                acc0 = __builtin_amdgcn_mfma_f32_16x16x32_f16(a1, wf[0][2], acc0, 0, 0, 0);
                acc1 = __builtin_amdgcn_mfma_f32_16x16x32_f16(a1, wf[1][2], acc1, 0, 0, 0);
                acc2 = __builtin_amdgcn_mfma_f32_16x16x32_f16(a1, wf[2][2], acc2, 0, 0, 0);
                acc3 = __builtin_amdgcn_mfma_f32_16x16x32_f16(a1, wf[3][2], acc3, 0, 0, 0);

                xr0 = v0.x; xr1 = v0.y; xr2 = v1.x; xr3 = v1.y; xr4 = v2.x; xr5 = v2.y;

                float* hw = &h1buf[1 - p][0][0];
                const int jc = 16 * lw + col;
#pragma unroll
                for (int r = 0; r < 4; ++r) {
                    float iv = sigf(acc0[r] + bias[0]);
                    float fv = sigf(acc1[r] + bias[1]);
                    float gv = tanh_fast(acc2[r] + bias[2]);
                    float ov = sigf(acc3[r] + bias[3]);
                    float* cp = (r == 0) ? &cst0 : (r == 1) ? &cst1 : (r == 2) ? &cst2 : &cst3;
                    float cn = fv * (*cp) + iv * gv;
                    *cp = cn;
                    hw[(4 * g4 + r) * HPAD + jc] = ov * tanh_fast(cn);
                }
            }
        } else {
            if (it >= 1) {   // layer-2 step t = it-1
                const f32x4* q0 = (const f32x4*)&h1buf[p][col][8 * g4];
                const f32x4* q1 = (const f32x4*)&h1buf[p][col][32 + 8 * g4];
                const f32x4* q2 = (const f32x4*)&h2buf[p][col][8 * g4];
                const f32x4* q3 = (const f32x4*)&h2buf[p][col][32 + 8 * g4];
                half8 a0 = pack8(q0[0], q0[1]);
                half8 a1 = pack8(q1[0], q1[1]);
                half8 a2 = pack8(q2[0], q2[1]);
                half8 a3 = pack8(q3[0], q3[1]);

                f32x4 acc0 = {0.f,0.f,0.f,0.f}, acc1 = {0.f,0.f,0.f,0.f};
                f32x4 acc2 = {0.f,0.f,0.f,0.f}, acc3 = {0.f,0.f,0.f,0.f};
                acc0 = __builtin_amdgcn_mfma_f32_16x16x32_f16(a0, wf[0][0], acc0, 0, 0, 0);
                acc1 = __builtin_amdgcn_mfma_f32_16x16x32_f16(a0, wf[1][0], acc1, 0, 0, 0);
                acc2 = __builtin_amdgcn_mfma_f32_16x16x32_f16(a0, wf[2][0], acc2, 0, 0, 0);
                acc3 = __builtin_amdgcn_mfma_f32_16x16x32_f16(a0, wf[3][0], acc3, 0, 0, 0);
                acc0 = __builtin_amdgcn_mfma_f32_16x16x32_f16(a1, wf[0][1], acc0, 0, 0, 0);
                acc1 = __builtin_amdgcn_mfma_f32_16x16x32_f16(a1, wf[1][1], acc1, 0, 0, 0);
                acc2 = __builtin_amdgcn_mfma_f32_16x16x32_f16(a1, wf[2][1], acc2, 0, 0, 0);
                acc3 = __builtin_amdgcn_mfma_f32_16x16x32_f16(a1, wf[3][1], acc3, 0, 0, 0);
                acc0 = __builtin_amdgcn_mfma_f32_16x16x32_f16(a2, wf[0][2], acc0, 0, 0, 0);
                acc1 = __builtin_amdgcn_mfma_f32_16x16x32_f16(a2, wf[1][2], acc1, 0, 0, 0);
                acc2 = __builtin_amdgcn_mfma_f32_16x16x32_f16(a2, wf[2][2], acc2, 0, 0, 0);
                acc3 = __builtin_amdgcn_mfma_f32_16x16x32_f16(a2, wf[3][2], acc3, 0, 0, 0);
                acc0 = __builtin_amdgcn_mfma_f32_16x16x32_f16(a3, wf[0][3], acc0, 0, 0, 0);
                acc1 = __builtin_amdgcn_mfma_f32_16x16x32_f16(a3, wf[1][3], acc1, 0, 0, 0);
                acc2 = __builtin_amdgcn_mfma_f32_16x16x32_f16(a3, wf[2][3], acc2, 0, 0, 0);
                acc3 = __builtin_amdgcn_mfma_f32_16x16x32_f16(a3, wf[3][3], acc3, 0, 0, 0);

                float* hw = &h2buf[1 - p][0][0];
                const int jc = 16 * lw + col;
#pragma unroll
                for (int r = 0; r < 4; ++r) {
                    float iv = sigf(acc0[r] + bias[0]);
                    float fv = sigf(acc1[r] + bias[1]);
                    float gv = tanh_fast(acc2[r] + bias[2]);
                    float ov = sigf(acc3[r] + bias[3]);
                    float* cp = (r == 0) ? &cst0 : (r == 1) ? &cst1 : (r == 2) ? &cst2 : &cst3;
                    float cn = fv * (*cp) + iv * gv;
                    *cp = cn;
                    hw[(4 * g4 + r) * HPAD + jc] = ov * tanh_fast(cn);
                }
            }
        }
        __syncthreads();
        p ^= 1;
    }

    // ---- FC head on h2(T-1) (now in h2buf[p]) ----
    {
        const int u = tid & 31, bb = tid >> 5;   // 16 batch x 32 units = 512 threads
        float s = b_fc1[u];
#pragma unroll 8
        for (int j = 0; j < 64; ++j) s = fmaf(W_fc1[u * 64 + j], h2buf[p][bb][j], s);
        fcbuf[bb][u] = fmaxf(s, 0.f);
    }
    __syncthreads();
    if (tid < 16) {
        float s = b_fc2[0];
#pragma unroll
        for (int k = 0; k < 32; ++k) s = fmaf(W_fc2[k], fcbuf[tid][k], s);
        out[b0 + tid] = s;
    }
}

extern "C" void kernel_launch(void* const* d_in, const int* in_sizes, int n_in,
                              void* d_out, int out_size, void* d_ws, size_t ws_size,
                              hipStream_t stream) {
    const float* x     = (const float*)d_in[0];
    const float* W_ih0 = (const float*)d_in[1];
    const float* W_hh0 = (const float*)d_in[2];
    const float* b_ih0 = (const float*)d_in[3];
    const float* b_hh0 = (const float*)d_in[4];
    const float* W_ih1 = (const float*)d_in[5];
    const float* W_hh1 = (const float*)d_in[6];
    const float* b_ih1 = (const float*)d_in[7];
    const float* b_hh1 = (const float*)d_in[8];
    const float* W_fc1 = (const float*)d_in[9];
    const float* b_fc1 = (const float*)d_in[10];
    const float* W_fc2 = (const float*)d_in[11];
    const float* b_fc2 = (const float*)d_in[12];
    float* out = (float*)d_out;

    const int B = in_sizes[0] / (T_STEPS * 6);   // 1024
    lstm_mfma_kernel<<<B / 16, 512, 0, stream>>>(
        x, W_ih0, W_hh0, b_ih0, b_hh0,
        W_ih1, W_hh1, b_ih1, b_hh1,
        W_fc1, b_fc1, W_fc2, b_fc2, out);
}

// Round 7
// 573.667 us; speedup vs baseline: 13.7705x; 1.5784x over previous
//
#include <hip/hip_runtime.h>

#define T_STEPS 512
#define HPAD 76   // LDS row pad (floats): 16B-aligned rows, ~2-way bank conflicts

typedef _Float16 half8 __attribute__((ext_vector_type(8)));
typedef float f32x4 __attribute__((ext_vector_type(4)));

// RAW v_rcp_f32 (~1 ulp). The plain "1.0f/x" without fast-math expands to the
// IEEE div sequence (v_div_scale+v_div_fmas+v_div_fixup, ~10 instrs + extra
// transcendentals); at 20 divisions/lane/step that was ~1000+ cyc/SIMD/step
// of the round-6 critical path (848us, 4000 cyc/step, VALUBusy 20%).
__device__ __forceinline__ float fastrcp(float v) { return __builtin_amdgcn_rcpf(v); }

__device__ __forceinline__ float sigf(float v) { return fastrcp(1.0f + __expf(-v)); }
__device__ __forceinline__ float tanh_fast(float v) {
    return 1.0f - 2.0f * fastrcp(__expf(2.0f * v) + 1.0f);
}

// 8 floats -> 8 fp16 (RTN via scalar casts)
__device__ __forceinline__ half8 pack8(f32x4 a, f32x4 b) {
    half8 r;
    r[0] = (_Float16)a[0]; r[1] = (_Float16)a[1];
    r[2] = (_Float16)a[2]; r[3] = (_Float16)a[3];
    r[4] = (_Float16)b[0]; r[5] = (_Float16)b[1];
    r[6] = (_Float16)b[2]; r[7] = (_Float16)b[3];
    return r;
}

// MFMA fragment maps (16x16x32):
//   A[16xK32]: row = lane&15, k = (lane>>4)*8 + i
//   B[K32x16]: col = lane&15, k = (lane>>4)*8 + i
//   D[16x16] : col = lane&15, row = (lane>>4)*4 + reg
// WG = 16 batch rows. Waves 0-3: layer1; waves 4-7: layer2 (one step behind).
// Wave lw owns j in [16lw,16lw+16) via col-tiles {lw,lw+4,lw+8,lw+12} so the
// 4 gate types for (batch,j) land in one lane's 4 accumulators -> in-register
// cell update. h crosses steps via padded LDS (fp32). padlds forces ~83KB LDS
// -> 1 WG/CU -> 2 waves/EU -> 256-VGPR grant tier (rounds 2-6: the allocator
// sizes VGPRs to the LDS-allowed max occupancy; attributes are ignored).
__global__ __launch_bounds__(512)
void lstm_mfma_kernel(const float* __restrict__ x,
                      const float* __restrict__ W_ih0, const float* __restrict__ W_hh0,
                      const float* __restrict__ b_ih0, const float* __restrict__ b_hh0,
                      const float* __restrict__ W_ih1, const float* __restrict__ W_hh1,
                      const float* __restrict__ b_ih1, const float* __restrict__ b_hh1,
                      const float* __restrict__ W_fc1, const float* __restrict__ b_fc1,
                      const float* __restrict__ W_fc2, const float* __restrict__ b_fc2,
                      float* __restrict__ out)
{
    const int tid  = threadIdx.x;
    const int lane = tid & 63;
    const int wid  = tid >> 6;      // 0..7
    const int lw   = wid & 3;       // wave index within role group
    const bool isL2 = wid >= 4;
    const int b0   = blockIdx.x * 16;
    const int col  = lane & 15;     // B-frag col / A-frag row
    const int g4   = lane >> 4;     // k-group

    __shared__ __align__(16) float h1buf[2][16][HPAD];
    __shared__ __align__(16) float h2buf[2][16][HPAD];
    __shared__ float fcbuf[16][32];
    __shared__ float padlds[15360];   // occupancy shaping only

    if (blockIdx.x == 0x7fffffff) {   // never true at grid=64; keeps padlds live
        padlds[tid] = (float)tid;
        out[0] = padlds[0];
    }

    // ---------------- weight fragments (one-time) ----------------
    // L1 chunks: 0 = x (k0..5 real, rest 0), 1..2 = W_hh0 k-halves
    // L2 chunks: 0..1 = W_ih1 (vs h1), 2..3 = W_hh1 (vs h2)
    half8 wf[4][4];
    float bias[4];
#pragma unroll
    for (int n = 0; n < 4; ++n) {
        const int grow = 16 * (lw + 4 * n) + col;   // gate row of tile n
        if (!isL2) {
            half8 wx;
#pragma unroll
            for (int i = 0; i < 8; ++i) wx[i] = (_Float16)0.f;
            if (g4 == 0) {
                const float2* wp = (const float2*)(W_ih0 + grow * 6);
                float2 w0 = wp[0], w1 = wp[1], w2 = wp[2];
                wx[0] = (_Float16)w0.x; wx[1] = (_Float16)w0.y;
                wx[2] = (_Float16)w1.x; wx[3] = (_Float16)w1.y;
                wx[4] = (_Float16)w2.x; wx[5] = (_Float16)w2.y;
            }
            wf[n][0] = wx;
#pragma unroll
            for (int c = 0; c < 2; ++c) {
                const f32x4* wp = (const f32x4*)(W_hh0 + grow * 64 + 32 * c + 8 * g4);
                wf[n][1 + c] = pack8(wp[0], wp[1]);
            }
            wf[n][3] = wf[n][0];  // unused in L1 path
            bias[n] = b_ih0[grow] + b_hh0[grow];
        } else {
#pragma unroll
            for (int c = 0; c < 2; ++c) {
                const f32x4* wp = (const f32x4*)(W_ih1 + grow * 64 + 32 * c + 8 * g4);
                wf[n][c] = pack8(wp[0], wp[1]);
            }
#pragma unroll
            for (int c = 0; c < 2; ++c) {
                const f32x4* wp = (const f32x4*)(W_hh1 + grow * 64 + 32 * c + 8 * g4);
                wf[n][2 + c] = pack8(wp[0], wp[1]);
            }
            bias[n] = b_ih1[grow] + b_hh1[grow];
        }
    }

    // zero both h double-buffers
    for (int i = tid; i < 2 * 16 * HPAD; i += 512) {
        (&h1buf[0][0][0])[i] = 0.f;
        (&h2buf[0][0][0])[i] = 0.f;
    }

    float cst0 = 0.f, cst1 = 0.f, cst2 = 0.f, cst3 = 0.f;  // cell state (4 batch rows)
    float xr0=0.f, xr1=0.f, xr2=0.f, xr3=0.f, xr4=0.f, xr5=0.f;
    if (!isL2) {   // x(t=0) prefetch; lane's batch = col (dup across g4, L1-cached)
        const float2* xp = (const float2*)(x + (size_t)(b0 + col) * T_STEPS * 6);
        float2 v0 = xp[0], v1 = xp[1], v2 = xp[2];
        xr0 = v0.x; xr1 = v0.y; xr2 = v1.x; xr3 = v1.y; xr4 = v2.x; xr5 = v2.y;
    }
    __syncthreads();

    int p = 0;
    for (int it = 0; it <= T_STEPS; ++it) {
        if (!isL2) {
            if (it < T_STEPS) {   // layer-1 step t = it
                half8 ax;
#pragma unroll
                for (int i = 0; i < 8; ++i) ax[i] = (_Float16)0.f;
                if (g4 == 0) {
                    ax[0] = (_Float16)xr0; ax[1] = (_Float16)xr1; ax[2] = (_Float16)xr2;
                    ax[3] = (_Float16)xr3; ax[4] = (_Float16)xr4; ax[5] = (_Float16)xr5;
                }
                // prefetch next x under this step's compute
                const int tn = (it + 1 < T_STEPS) ? (it + 1) : (T_STEPS - 1);
                const float2* xp = (const float2*)(x + ((size_t)(b0 + col) * T_STEPS + tn) * 6);
                float2 v0 = xp[0], v1 = xp[1], v2 = xp[2];

                const f32x4* h0p = (const f32x4*)&h1buf[p][col][8 * g4];
                const f32x4* h1p = (const f32x4*)&h1buf[p][col][32 + 8 * g4];
                half8 a0 = pack8(h0p[0], h0p[1]);
                half8 a1 = pack8(h1p[0], h1p[1]);

                f32x4 acc0 = {0.f,0.f,0.f,0.f}, acc1 = {0.f,0.f,0.f,0.f};
                f32x4 acc2 = {0.f,0.f,0.f,0.f}, acc3 = {0.f,0.f,0.f,0.f};
                acc0 = __builtin_amdgcn_mfma_f32_16x16x32_f16(ax, wf[0][0], acc0, 0, 0, 0);
                acc1 = __builtin_amdgcn_mfma_f32_16x16x32_f16(ax, wf[1][0], acc1, 0, 0, 0);
                acc2 = __builtin_amdgcn_mfma_f32_16x16x32_f16(ax, wf[2][0], acc2, 0, 0, 0);
                acc3 = __builtin_amdgcn_mfma_f32_16x16x32_f16(ax, wf[3][0], acc3, 0, 0, 0);
                acc0 = __builtin_amdgcn_mfma_f32_16x16x32_f16(a0, wf[0][1], acc0, 0, 0, 0);
                acc1 = __builtin_amdgcn_mfma_f32_16x16x32_f16(a0, wf[1][1], acc1, 0, 0, 0);
                acc2 = __builtin_amdgcn_mfma_f32_16x16x32_f16(a0, wf[2][1], acc2, 0, 0, 0);
                acc3 = __builtin_amdgcn_mfma_f32_16x16x32_f16(a0, wf[3][1], acc3, 0, 0, 0);
                acc0 = __builtin_amdgcn_mfma_f32_16x16x32_f16(a1, wf[0][2], acc0, 0, 0, 0);
                acc1 = __builtin_amdgcn_mfma_f32_16x16x32_f16(a1, wf[1][2], acc1, 0, 0, 0);
                acc2 = __builtin_amdgcn_mfma_f32_16x16x32_f16(a1, wf[2][2], acc2, 0, 0, 0);
                acc3 = __builtin_amdgcn_mfma_f32_16x16x32_f16(a1, wf[3][2], acc3, 0, 0, 0);

                xr0 = v0.x; xr1 = v0.y; xr2 = v1.x; xr3 = v1.y; xr4 = v2.x; xr5 = v2.y;

                float* hw = &h1buf[1 - p][0][0];
                const int jc = 16 * lw + col;
#pragma unroll
                for (int r = 0; r < 4; ++r) {
                    float iv = sigf(acc0[r] + bias[0]);
                    float fv = sigf(acc1[r] + bias[1]);
                    float gv = tanh_fast(acc2[r] + bias[2]);
                    float ov = sigf(acc3[r] + bias[3]);
                    float* cp = (r == 0) ? &cst0 : (r == 1) ? &cst1 : (r == 2) ? &cst2 : &cst3;
                    float cn = fv * (*cp) + iv * gv;
                    *cp = cn;
                    hw[(4 * g4 + r) * HPAD + jc] = ov * tanh_fast(cn);
                }
            }
        } else {
            if (it >= 1) {   // layer-2 step t = it-1
                const f32x4* q0 = (const f32x4*)&h1buf[p][col][8 * g4];
                const f32x4* q1 = (const f32x4*)&h1buf[p][col][32 + 8 * g4];
                const f32x4* q2 = (const f32x4*)&h2buf[p][col][8 * g4];
                const f32x4* q3 = (const f32x4*)&h2buf[p][col][32 + 8 * g4];
                half8 a0 = pack8(q0[0], q0[1]);
                half8 a1 = pack8(q1[0], q1[1]);
                half8 a2 = pack8(q2[0], q2[1]);
                half8 a3 = pack8(q3[0], q3[1]);

                f32x4 acc0 = {0.f,0.f,0.f,0.f}, acc1 = {0.f,0.f,0.f,0.f};
                f32x4 acc2 = {0.f,0.f,0.f,0.f}, acc3 = {0.f,0.f,0.f,0.f};
                acc0 = __builtin_amdgcn_mfma_f32_16x16x32_f16(a0, wf[0][0], acc0, 0, 0, 0);
                acc1 = __builtin_amdgcn_mfma_f32_16x16x32_f16(a0, wf[1][0], acc1, 0, 0, 0);
                acc2 = __builtin_amdgcn_mfma_f32_16x16x32_f16(a0, wf[2][0], acc2, 0, 0, 0);
                acc3 = __builtin_amdgcn_mfma_f32_16x16x32_f16(a0, wf[3][0], acc3, 0, 0, 0);
                acc0 = __builtin_amdgcn_mfma_f32_16x16x32_f16(a1, wf[0][1], acc0, 0, 0, 0);
                acc1 = __builtin_amdgcn_mfma_f32_16x16x32_f16(a1, wf[1][1], acc1, 0, 0, 0);
                acc2 = __builtin_amdgcn_mfma_f32_16x16x32_f16(a1, wf[2][1], acc2, 0, 0, 0);
                acc3 = __builtin_amdgcn_mfma_f32_16x16x32_f16(a1, wf[3][1], acc3, 0, 0, 0);
                acc0 = __builtin_amdgcn_mfma_f32_16x16x32_f16(a2, wf[0][2], acc0, 0, 0, 0);
                acc1 = __builtin_amdgcn_mfma_f32_16x16x32_f16(a2, wf[1][2], acc1, 0, 0, 0);
                acc2 = __builtin_amdgcn_mfma_f32_16x16x32_f16(a2, wf[2][2], acc2, 0, 0, 0);
                acc3 = __builtin_amdgcn_mfma_f32_16x16x32_f16(a2, wf[3][2], acc3, 0, 0, 0);
                acc0 = __builtin_amdgcn_mfma_f32_16x16x32_f16(a3, wf[0][3], acc0, 0, 0, 0);
                acc1 = __builtin_amdgcn_mfma_f32_16x16x32_f16(a3, wf[1][3], acc1, 0, 0, 0);
                acc2 = __builtin_amdgcn_mfma_f32_16x16x32_f16(a3, wf[2][3], acc2, 0, 0, 0);
                acc3 = __builtin_amdgcn_mfma_f32_16x16x32_f16(a3, wf[3][3], acc3, 0, 0, 0);

                float* hw = &h2buf[1 - p][0][0];
                const int jc = 16 * lw + col;
#pragma unroll
                for (int r = 0; r < 4; ++r) {
                    float iv = sigf(acc0[r] + bias[0]);
                    float fv = sigf(acc1[r] + bias[1]);
                    float gv = tanh_fast(acc2[r] + bias[2]);
                    float ov = sigf(acc3[r] + bias[3]);
                    float* cp = (r == 0) ? &cst0 : (r == 1) ? &cst1 : (r == 2) ? &cst2 : &cst3;
                    float cn = fv * (*cp) + iv * gv;
                    *cp = cn;
                    hw[(4 * g4 + r) * HPAD + jc] = ov * tanh_fast(cn);
                }
            }
        }
        __syncthreads();
        p ^= 1;
    }

    // ---- FC head on h2(T-1) (now in h2buf[p]) ----
    {
        const int u = tid & 31, bb = tid >> 5;   // 16 batch x 32 units = 512 threads
        float s = b_fc1[u];
#pragma unroll 8
        for (int j = 0; j < 64; ++j) s = fmaf(W_fc1[u * 64 + j], h2buf[p][bb][j], s);
        fcbuf[bb][u] = fmaxf(s, 0.f);
    }
    __syncthreads();
    if (tid < 16) {
        float s = b_fc2[0];
#pragma unroll
        for (int k = 0; k < 32; ++k) s = fmaf(W_fc2[k], fcbuf[tid][k], s);
        out[b0 + tid] = s;
    }
}

extern "C" void kernel_launch(void* const* d_in, const int* in_sizes, int n_in,
                              void* d_out, int out_size, void* d_ws, size_t ws_size,
                              hipStream_t stream) {
    const float* x     = (const float*)d_in[0];
    const float* W_ih0 = (const float*)d_in[1];
    const float* W_hh0 = (const float*)d_in[2];
    const float* b_ih0 = (const float*)d_in[3];
    const float* b_hh0 = (const float*)d_in[4];
    const float* W_ih1 = (const float*)d_in[5];
    const float* W_hh1 = (const float*)d_in[6];
    const float* b_ih1 = (const float*)d_in[7];
    const float* b_hh1 = (const float*)d_in[8];
    const float* W_fc1 = (const float*)d_in[9];
    const float* b_fc1 = (const float*)d_in[10];
    const float* W_fc2 = (const float*)d_in[11];
    const float* b_fc2 = (const float*)d_in[12];
    float* out = (float*)d_out;

    const int B = in_sizes[0] / (T_STEPS * 6);   // 1024
    lstm_mfma_kernel<<<B / 16, 512, 0, stream>>>(
        x, W_ih0, W_hh0, b_ih0, b_hh0,
        W_ih1, W_hh1, b_ih1, b_hh1,
        W_fc1, b_fc1, W_fc2, b_fc2, out);
}